// Round 1
// baseline (131.932 us; speedup 1.0000x reference)
//
#include <hip/hip_runtime.h>

#define DIMC 256
#define NHEAD 8
#define NP 24        // patches per side
#define NPIX 9216    // 96*96

// One block per (b, head, patch). Computes 16 needed query rows of the
// 64-position patch attention and writes the (s x s x d) slice to mid.
__global__ __launch_bounds__(256) void patch_attn(
    const float* __restrict__ x,
    const float* __restrict__ qkv_w,
    const float* __restrict__ qkv_b,
    const float* __restrict__ pos_table,
    float* __restrict__ mid)
{
    const int t = threadIdx.x;
    const int bid = blockIdx.x;              // ((b*8+head)*576 + patch)
    const int patch = bid % 576;
    const int bh = bid / 576;
    const int head = bh & 7;
    const int b = bh >> 3;
    const int ni = patch / NP, nj = patch % NP;

    __shared__ float xk[64][33];   // +1 pad: kill bank conflicts
    __shared__ float xv[64][33];
    __shared__ float xq[16][33];
    __shared__ float sp[16][65];

    const int c0 = head * 32;
    const float qscale = 0.17677669529663687f;  // 32^-0.5

    // Load x patch (64 pos x 32 ch) once; q/k/v are affine transforms of it.
    for (int i = 0; i < 8; ++i) {
        int e = i * 256 + t;
        int pos = e & 63;            // consecutive threads -> consecutive cols
        int d   = e >> 6;
        int pi = pos >> 3, pj = pos & 7;
        int row = min(4 * ni + pi, 95);   // edge padding (bottom/right only)
        int col = min(4 * nj + pj, 95);
        int c = c0 + d;
        float xval = x[(((size_t)b * DIMC + c) * 96 + row) * 96 + col];
        xk[pos][d] = xval * qkv_w[256 + c] + qkv_b[256 + c];
        xv[pos][d] = xval * qkv_w[512 + c] + qkv_b[512 + c];
        if (pi < 4 && pj < 4)
            xq[pi * 4 + pj][d] = (xval * qkv_w[c] + qkv_b[c]) * qscale;
    }
    __syncthreads();

    // Scores: thread t -> q-row qr = t>>4, 4 k-columns.
    const int qr  = t >> 4;
    const int l16 = t & 15;
    const int qi = qr >> 2, qj = qr & 3;   // qr = pi*4 + pj, pi,pj in [0,4)

    float sc[4];
    #pragma unroll
    for (int j = 0; j < 4; ++j) {
        int kk = l16 * 4 + j;
        int ki = kk >> 3, kj = kk & 7;
        float dot = 0.f;
        #pragma unroll
        for (int d = 0; d < 32; ++d)
            dot += xq[qr][d] * xk[kk][d];
        sc[j] = dot + pos_table[((qi - ki + 7) * 15 + (qj - kj + 7)) * NHEAD + head];
    }

    // Row softmax across the 16 lanes owning this row (4 vals each).
    float mx = fmaxf(fmaxf(sc[0], sc[1]), fmaxf(sc[2], sc[3]));
    for (int off = 8; off; off >>= 1)
        mx = fmaxf(mx, __shfl_xor(mx, off, 16));
    float sum = 0.f;
    #pragma unroll
    for (int j = 0; j < 4; ++j) { sc[j] = __expf(sc[j] - mx); sum += sc[j]; }
    for (int off = 8; off; off >>= 1)
        sum += __shfl_xor(sum, off, 16);
    float inv = 1.0f / sum;
    #pragma unroll
    for (int j = 0; j < 4; ++j)
        sp[qr][l16 * 4 + j] = sc[j] * inv;
    __syncthreads();

    // PV: thread t -> (qr, two d values)
    const int d0 = l16 * 2;
    float a0 = 0.f, a1 = 0.f;
    for (int k = 0; k < 64; ++k) {
        float p = sp[qr][k];
        a0 += p * xv[k][d0];
        a1 += p * xv[k][d0 + 1];
    }
    const int hh = ni * 4 + qi, ww = nj * 4 + qj;
    size_t obase = (((size_t)b * DIMC + c0 + d0) * 96 + hh) * 96 + ww;
    mid[obase] = a0;
    mid[obase + (size_t)NPIX] = a1;
}

// y[b,o,pix] = sum_c w[o,c] * mid[b,c,pix] — 64(o) x 64(pix) tile per block,
// 4x4 register accumulators per thread, K=256 in 4 LDS-staged chunks.
__global__ __launch_bounds__(256) void proj(
    const float* __restrict__ w,     // [256][256]
    const float* __restrict__ mid,   // [B][256][9216]
    float* __restrict__ y)
{
    const int t  = threadIdx.x;
    const int tx = t & 15;           // pixel dir
    const int ty = t >> 4;           // o dir
    const int p0 = blockIdx.x * 64;  // pixel tile within image
    const int o0 = blockIdx.y * 64;
    const int b  = blockIdx.z;

    __shared__ float mt[64][65];
    __shared__ float wt[64][65];

    float acc[4][4];
    #pragma unroll
    for (int i = 0; i < 4; ++i)
        #pragma unroll
        for (int j = 0; j < 4; ++j) acc[i][j] = 0.f;

    const float* midb = mid + (size_t)b * DIMC * NPIX;

    for (int cc = 0; cc < 256; cc += 64) {
        __syncthreads();
        #pragma unroll
        for (int i = 0; i < 16; ++i) {           // mid tile: coalesced rows
            int e = i * 256 + t;
            int cl = e >> 6, pix = e & 63;
            mt[cl][pix] = midb[(size_t)(cc + cl) * NPIX + p0 + pix];
        }
        #pragma unroll
        for (int i = 0; i < 16; ++i) {           // w tile, transposed to [c][o]
            int e = i * 256 + t;
            int ol = e >> 6, cl = e & 63;
            wt[cl][ol] = w[(o0 + ol) * 256 + cc + cl];
        }
        __syncthreads();
        for (int cl = 0; cl < 64; ++cl) {
            float rw[4], rm[4];
            #pragma unroll
            for (int i = 0; i < 4; ++i) rw[i] = wt[cl][ty + i * 16];
            #pragma unroll
            for (int j = 0; j < 4; ++j) rm[j] = mt[cl][tx + j * 16];
            #pragma unroll
            for (int i = 0; i < 4; ++i)
                #pragma unroll
                for (int j = 0; j < 4; ++j)
                    acc[i][j] += rw[i] * rm[j];
        }
    }

    float* yb = y + ((size_t)b * DIMC + o0) * NPIX + p0;
    #pragma unroll
    for (int i = 0; i < 4; ++i)
        #pragma unroll
        for (int j = 0; j < 4; ++j)
            yb[(size_t)(ty + i * 16) * NPIX + tx + j * 16] = acc[i][j];
}

extern "C" void kernel_launch(void* const* d_in, const int* in_sizes, int n_in,
                              void* d_out, int out_size, void* d_ws, size_t ws_size,
                              hipStream_t stream) {
    const float* x         = (const float*)d_in[0];
    const float* qkv_w     = (const float*)d_in[1];
    const float* qkv_b     = (const float*)d_in[2];
    const float* out_w     = (const float*)d_in[3];
    const float* pos_table = (const float*)d_in[4];
    float* y   = (float*)d_out;
    float* mid = (float*)d_ws;   // B*C*96*96 fp32 = 18.9 MB scratch

    patch_attn<<<dim3(2 * NHEAD * 576), dim3(256), 0, stream>>>(
        x, qkv_w, qkv_b, pos_table, mid);
    proj<<<dim3(NPIX / 64, DIMC / 64, 2), dim3(256), 0, stream>>>(
        out_w, mid, y);
}

// Round 2
// 70.107 us; speedup vs baseline: 1.8819x; 1.8819x over previous
//
#include <hip/hip_runtime.h>

typedef float f4 __attribute__((ext_vector_type(4)));
typedef float f32x4 __attribute__((ext_vector_type(4)));
typedef __bf16 bf16x8 __attribute__((ext_vector_type(8)));

#define NPATCH 576
#define NPSIDE 24

// One wave per (b, head, patch). 4 waves per block, independent work,
// __syncthreads only to order own-wave LDS (cheap: waves are symmetric).
__global__ __launch_bounds__(256) void patch_attn(
    const float* __restrict__ x,
    const float* __restrict__ qkv_w,
    const float* __restrict__ qkv_b,
    const float* __restrict__ pos_table,
    float* __restrict__ mid)
{
    // pads: Kb/Qb rows 40 bf16 (80B) -> b128 frag reads 2-way; VT/Ps rows 72
    // bf16 (144B) -> 2-way; all rows 16B aligned for b128.
    __shared__ __bf16 Kb[4][64][40];
    __shared__ __bf16 VT[4][32][72];
    __shared__ __bf16 Qb[4][16][40];
    __shared__ __bf16 Ps[4][16][72];

    const int t  = threadIdx.x;
    const int wv = t >> 6;
    const int l  = t & 63;

    int bid = blockIdx.x;
    bid = (bid & 7) * 288 + (bid >> 3);      // XCD swizzle, 2304 = 8*288
    const int gp    = bid * 4 + wv;
    const int patch = gp % NPATCH;
    const int bh    = gp / NPATCH;
    const int head  = bh & 7;
    const int b     = bh >> 3;
    const int ni = patch / NPSIDE, nj = patch % NPSIDE;
    const int c0 = head * 32;

    // ---- staging: lane l <-> patch position (pi,pj) ----
    const int pi = l >> 3, pj = l & 7;
    const int row = min(4 * ni + pi, 95);    // edge padding
    const int col = min(4 * nj + pj, 95);
    const bool isq = (pi < 4) && (pj < 4);
    const int qr = (pi << 2) | pj;
    const float qscale = 0.17677669529663687f;

    const float* xptr = x + (((size_t)b * 256 + c0) * 96 + row) * 96 + col;

    #pragma unroll
    for (int d8 = 0; d8 < 4; ++d8) {
        bf16x8 kv, qv;
        #pragma unroll
        for (int j = 0; j < 8; ++j) {
            const int d = d8 * 8 + j;
            const int c = c0 + d;
            const float xv = xptr[(size_t)d * 9216];
            kv[j] = (__bf16)(xv * qkv_w[256 + c] + qkv_b[256 + c]);
            VT[wv][d][l] = (__bf16)(xv * qkv_w[512 + c] + qkv_b[512 + c]);
            qv[j] = (__bf16)((xv * qkv_w[c] + qkv_b[c]) * qscale);
        }
        *(bf16x8*)&Kb[wv][l][d8 * 8] = kv;
        if (isq) *(bf16x8*)&Qb[wv][qr][d8 * 8] = qv;
    }
    __syncthreads();

    // ---- QK^T: S(16x64) via 4 x mfma_16x16x32 ----
    const int l16 = l & 15, lg = l >> 4;
    const f32x4 zf = {0.f, 0.f, 0.f, 0.f};
    bf16x8 qf = *(const bf16x8*)&Qb[wv][l16][lg * 8];
    f32x4 sacc[4];
    #pragma unroll
    for (int t4 = 0; t4 < 4; ++t4) {
        bf16x8 kf = *(const bf16x8*)&Kb[wv][l16 + 16 * t4][lg * 8];
        sacc[t4] = __builtin_amdgcn_mfma_f32_16x16x32_bf16(qf, kf, zf, 0, 0, 0);
    }

    // ---- bias + row softmax (rows (lg*4+r), cols spread over l16 x 4 tiles) ----
    float sv[4][4];
    float rinv[4];
    #pragma unroll
    for (int r = 0; r < 4; ++r) {
        const int qrow = lg * 4 + r;
        const int qi = qrow >> 2, qj = qrow & 3;
        float m = -1e30f;
        #pragma unroll
        for (int t4 = 0; t4 < 4; ++t4) {
            const int kcol = l16 + 16 * t4;
            const int ki = kcol >> 3, kj = kcol & 7;
            const float s = sacc[t4][r]
                + pos_table[((qi - ki + 7) * 15 + (qj - kj + 7)) * 8 + head];
            sv[t4][r] = s;
            m = fmaxf(m, s);
        }
        #pragma unroll
        for (int off = 8; off >= 1; off >>= 1)
            m = fmaxf(m, __shfl_xor(m, off, 16));
        float sum = 0.f;
        #pragma unroll
        for (int t4 = 0; t4 < 4; ++t4) {
            const float p = __expf(sv[t4][r] - m);
            sv[t4][r] = p;
            sum += p;
        }
        #pragma unroll
        for (int off = 8; off >= 1; off >>= 1)
            sum += __shfl_xor(sum, off, 16);
        rinv[r] = 1.0f / sum;
        #pragma unroll
        for (int t4 = 0; t4 < 4; ++t4)
            Ps[wv][qrow][l16 + 16 * t4] = (__bf16)sv[t4][r];
    }
    __syncthreads();

    // ---- PV: O(16x32) = P(16x64) * V(64x32), 2 k-tiles x 2 n-tiles ----
    f32x4 oa = zf, ob = zf;
    #pragma unroll
    for (int kt = 0; kt < 2; ++kt) {
        bf16x8 pf = *(const bf16x8*)&Ps[wv][l16][lg * 8 + 32 * kt];
        bf16x8 v0 = *(const bf16x8*)&VT[wv][l16][lg * 8 + 32 * kt];
        bf16x8 v1 = *(const bf16x8*)&VT[wv][l16 + 16][lg * 8 + 32 * kt];
        oa = __builtin_amdgcn_mfma_f32_16x16x32_bf16(pf, v0, oa, 0, 0, 0);
        ob = __builtin_amdgcn_mfma_f32_16x16x32_bf16(pf, v1, ob, 0, 0, 0);
    }

    // mid layout: [b][patch*16 + qrow][c]  (pixel-major, c contiguous)
    float* mb = mid + ((size_t)b * 9216 + patch * 16) * 256 + c0;
    #pragma unroll
    for (int r = 0; r < 4; ++r) {
        const int qrow = lg * 4 + r;
        mb[(size_t)qrow * 256 + l16]      = oa[r] * rinv[r];
        mb[(size_t)qrow * 256 + 16 + l16] = ob[r] * rinv[r];
    }
}

// y[b,o,hh,ww] = sum_c w[o,c] * mid[b,pslot,c]. 64 o x 64 pslot tile,
// dot-product form: K-contiguous LDS rows, float4 partial-sum accumulators.
__global__ __launch_bounds__(256) void proj(
    const float* __restrict__ wmat,   // [256][256]
    const float* __restrict__ mid,    // [B][9216][256] pixel-major
    float* __restrict__ y)
{
    __shared__ float mt[64][68];
    __shared__ float wt[64][68];

    const int t  = threadIdx.x;
    const int tx = t & 15;
    const int ty = t >> 4;
    int bx = blockIdx.x;
    bx = (bx & 7) * 18 + (bx >> 3);          // XCD swizzle, 144 = 8*18
    const int p0 = bx * 64;
    const int o0 = blockIdx.y * 64;
    const int b  = blockIdx.z;

    f4 acc[4][4];
    #pragma unroll
    for (int i = 0; i < 4; ++i)
        #pragma unroll
        for (int j = 0; j < 4; ++j) acc[i][j] = (f4){0.f, 0.f, 0.f, 0.f};

    const float* midb = mid + (size_t)b * 9216 * 256;

    for (int cc = 0; cc < 256; cc += 64) {
        __syncthreads();
        #pragma unroll
        for (int i = 0; i < 4; ++i) {
            const int r = ty + 16 * i;       // 0..63
            *(f4*)&mt[r][4 * tx] =
                *(const f4*)&midb[(size_t)(p0 + r) * 256 + cc + 4 * tx];
            *(f4*)&wt[r][4 * tx] =
                *(const f4*)&wmat[(size_t)(o0 + r) * 256 + cc + 4 * tx];
        }
        __syncthreads();
        #pragma unroll
        for (int c4 = 0; c4 < 16; ++c4) {
            f4 rm[4], rw[4];
            #pragma unroll
            for (int j = 0; j < 4; ++j) rm[j] = *(const f4*)&mt[tx + 16 * j][4 * c4];
            #pragma unroll
            for (int i = 0; i < 4; ++i) rw[i] = *(const f4*)&wt[ty + 16 * i][4 * c4];
            #pragma unroll
            for (int i = 0; i < 4; ++i)
                #pragma unroll
                for (int j = 0; j < 4; ++j)
                    acc[i][j] += rw[i] * rm[j];
        }
    }

    #pragma unroll
    for (int i = 0; i < 4; ++i) {
        const int o = o0 + ty + 16 * i;
        #pragma unroll
        for (int j = 0; j < 4; ++j) {
            const int ps = p0 + tx + 16 * j;
            const int patch = ps >> 4, qrr = ps & 15;
            const int hh = (patch / NPSIDE) * 4 + (qrr >> 2);
            const int ww = (patch % NPSIDE) * 4 + (qrr & 3);
            const float v = acc[i][j].x + acc[i][j].y + acc[i][j].z + acc[i][j].w;
            y[((size_t)b * 256 + o) * 9216 + hh * 96 + ww] = v;
        }
    }
}

extern "C" void kernel_launch(void* const* d_in, const int* in_sizes, int n_in,
                              void* d_out, int out_size, void* d_ws, size_t ws_size,
                              hipStream_t stream) {
    const float* x         = (const float*)d_in[0];
    const float* qkv_w     = (const float*)d_in[1];
    const float* qkv_b     = (const float*)d_in[2];
    const float* out_w     = (const float*)d_in[3];
    const float* pos_table = (const float*)d_in[4];
    float* y   = (float*)d_out;
    float* mid = (float*)d_ws;   // 2*9216*256 fp32 = 18.9 MB, pixel-major

    patch_attn<<<dim3(2304), dim3(256), 0, stream>>>(
        x, qkv_w, qkv_b, pos_table, mid);
    proj<<<dim3(144, 4, 2), dim3(256), 0, stream>>>(
        out_w, mid, y);
}

// Round 4
// 67.389 us; speedup vs baseline: 1.9578x; 1.0403x over previous
//
#include <hip/hip_runtime.h>

typedef float f4 __attribute__((ext_vector_type(4)));
typedef float f32x4 __attribute__((ext_vector_type(4)));
typedef __bf16 bf16x8 __attribute__((ext_vector_type(8)));

#define NPATCH 576
#define NPSIDE 24

// One wave per (b, head, patch). 4 waves per block, independent work.
__global__ __launch_bounds__(256) void patch_attn(
    const float* __restrict__ x,
    const float* __restrict__ qkv_w,
    const float* __restrict__ qkv_b,
    const float* __restrict__ pos_table,
    __bf16* __restrict__ mid)
{
    __shared__ __bf16 Kb[4][64][40];
    __shared__ __bf16 VT[4][32][72];
    __shared__ __bf16 Qb[4][16][40];
    __shared__ __bf16 Ps[4][16][72];

    const int t  = threadIdx.x;
    const int wv = t >> 6;
    const int l  = t & 63;

    int bid = blockIdx.x;
    bid = (bid & 7) * 288 + (bid >> 3);      // XCD swizzle, 2304 = 8*288
    const int gp    = bid * 4 + wv;
    const int patch = gp % NPATCH;
    const int bh    = gp / NPATCH;
    const int head  = bh & 7;
    const int b     = bh >> 3;
    const int ni = patch / NPSIDE, nj = patch % NPSIDE;
    const int c0 = head * 32;

    const int pi = l >> 3, pj = l & 7;
    const int row = min(4 * ni + pi, 95);    // edge padding
    const int col = min(4 * nj + pj, 95);
    const bool isq = (pi < 4) && (pj < 4);
    const int qr = (pi << 2) | pj;
    const float qscale = 0.17677669529663687f;

    const float* xptr = x + (((size_t)b * 256 + c0) * 96 + row) * 96 + col;

    #pragma unroll
    for (int d8 = 0; d8 < 4; ++d8) {
        bf16x8 kv, qv;
        #pragma unroll
        for (int j = 0; j < 8; ++j) {
            const int d = d8 * 8 + j;
            const int c = c0 + d;
            const float xv = xptr[(size_t)d * 9216];
            kv[j] = (__bf16)(xv * qkv_w[256 + c] + qkv_b[256 + c]);
            VT[wv][d][l] = (__bf16)(xv * qkv_w[512 + c] + qkv_b[512 + c]);
            qv[j] = (__bf16)((xv * qkv_w[c] + qkv_b[c]) * qscale);
        }
        *(bf16x8*)&Kb[wv][l][d8 * 8] = kv;
        if (isq) *(bf16x8*)&Qb[wv][qr][d8 * 8] = qv;
    }
    __syncthreads();

    // ---- QK^T: S(16x64) via 4 x mfma_16x16x32 ----
    const int l16 = l & 15, lg = l >> 4;
    const f32x4 zf = {0.f, 0.f, 0.f, 0.f};
    bf16x8 qf = *(const bf16x8*)&Qb[wv][l16][lg * 8];
    f32x4 sacc[4];
    #pragma unroll
    for (int t4 = 0; t4 < 4; ++t4) {
        bf16x8 kf = *(const bf16x8*)&Kb[wv][l16 + 16 * t4][lg * 8];
        sacc[t4] = __builtin_amdgcn_mfma_f32_16x16x32_bf16(qf, kf, zf, 0, 0, 0);
    }

    // ---- bias + row softmax ----
    float sv[4][4];
    float rinv[4];
    #pragma unroll
    for (int r = 0; r < 4; ++r) {
        const int qrow = lg * 4 + r;
        const int qi = qrow >> 2, qj = qrow & 3;
        float m = -1e30f;
        #pragma unroll
        for (int t4 = 0; t4 < 4; ++t4) {
            const int kcol = l16 + 16 * t4;
            const int ki = kcol >> 3, kj = kcol & 7;
            const float s = sacc[t4][r]
                + pos_table[((qi - ki + 7) * 15 + (qj - kj + 7)) * 8 + head];
            sv[t4][r] = s;
            m = fmaxf(m, s);
        }
        #pragma unroll
        for (int off = 8; off >= 1; off >>= 1)
            m = fmaxf(m, __shfl_xor(m, off, 16));
        float sum = 0.f;
        #pragma unroll
        for (int t4 = 0; t4 < 4; ++t4) {
            const float p = __expf(sv[t4][r] - m);
            sv[t4][r] = p;
            sum += p;
        }
        #pragma unroll
        for (int off = 8; off >= 1; off >>= 1)
            sum += __shfl_xor(sum, off, 16);
        rinv[r] = 1.0f / sum;
        #pragma unroll
        for (int t4 = 0; t4 < 4; ++t4)
            Ps[wv][qrow][l16 + 16 * t4] = (__bf16)sv[t4][r];
    }
    __syncthreads();

    // ---- PV: O(16x32) = P(16x64) * V(64x32) ----
    f32x4 oa = zf, ob = zf;
    #pragma unroll
    for (int kt = 0; kt < 2; ++kt) {
        bf16x8 pf = *(const bf16x8*)&Ps[wv][l16][lg * 8 + 32 * kt];
        bf16x8 v0 = *(const bf16x8*)&VT[wv][l16][lg * 8 + 32 * kt];
        bf16x8 v1 = *(const bf16x8*)&VT[wv][l16 + 16][lg * 8 + 32 * kt];
        oa = __builtin_amdgcn_mfma_f32_16x16x32_bf16(pf, v0, oa, 0, 0, 0);
        ob = __builtin_amdgcn_mfma_f32_16x16x32_bf16(pf, v1, ob, 0, 0, 0);
    }

    // mid layout: [b][patch*16 + qrow][c] bf16, c contiguous
    __bf16* mb = mid + ((size_t)b * 9216 + patch * 16) * 256 + c0;
    #pragma unroll
    for (int r = 0; r < 4; ++r) {
        const int qrow = lg * 4 + r;
        mb[(size_t)qrow * 256 + l16]      = (__bf16)(oa[r] * rinv[r]);
        mb[(size_t)qrow * 256 + 16 + l16] = (__bf16)(ob[r] * rinv[r]);
    }
}

// y[b,o,pix] = sum_c w[o,c]*mid[b,pix,c] as bf16 MFMA, no LDS.
// Block: 64 o x 128 pix; wave wv owns o-sub 16*wv x all 128 pix.
__global__ __launch_bounds__(256) void proj(
    const float* __restrict__ wmat,   // [256][256] fp32
    const __bf16* __restrict__ mid,   // [B][9216][256] bf16
    float* __restrict__ y)
{
    const int t  = threadIdx.x;
    const int wv = t >> 6;
    const int l  = t & 63;
    const int l16 = l & 15, lg = l >> 4;

    int bx = blockIdx.x;
    bx = (bx & 7) * 9 + (bx >> 3);           // XCD swizzle, 72 = 8*9
    const int p0 = bx * 128;                 // 72 tiles * 128 pix = 9216
    const int o0 = blockIdx.y * 64 + wv * 16;
    const int b  = blockIdx.z;

    const float* wrow = wmat + (size_t)(o0 + l16) * 256;
    const __bf16* midb = mid + (size_t)b * 9216 * 256;

    f32x4 acc[8];
    #pragma unroll
    for (int nt = 0; nt < 8; ++nt) acc[nt] = (f32x4){0.f, 0.f, 0.f, 0.f};

    #pragma unroll
    for (int kt = 0; kt < 8; ++kt) {
        const int cb = kt * 32 + lg * 8;
        // A fragment: 8 fp32 from w, convert to bf16
        const f4 a0 = *(const f4*)&wrow[cb];
        const f4 a1 = *(const f4*)&wrow[cb + 4];
        bf16x8 af;
        #pragma unroll
        for (int j = 0; j < 4; ++j) { af[j] = (__bf16)a0[j]; af[4 + j] = (__bf16)a1[j]; }
        #pragma unroll
        for (int nt = 0; nt < 8; ++nt) {
            const bf16x8 bfr =
                *(const bf16x8*)&midb[(size_t)(p0 + nt * 16 + l16) * 256 + cb];
            acc[nt] = __builtin_amdgcn_mfma_f32_16x16x32_bf16(af, bfr, acc[nt], 0, 0, 0);
        }
    }

    // D layout: col = l16 -> pix-sub, row = lg*4+r -> o-sub
    #pragma unroll
    for (int nt = 0; nt < 8; ++nt) {
        const int ps = p0 + nt * 16 + l16;
        const int patch = ps >> 4, qrr = ps & 15;
        const int hh = (patch / NPSIDE) * 4 + (qrr >> 2);
        const int ww = (patch % NPSIDE) * 4 + (qrr & 3);
        #pragma unroll
        for (int r = 0; r < 4; ++r) {
            const int o = o0 + lg * 4 + r;
            y[((size_t)b * 256 + o) * 9216 + hh * 96 + ww] = acc[nt][r];
        }
    }
}

extern "C" void kernel_launch(void* const* d_in, const int* in_sizes, int n_in,
                              void* d_out, int out_size, void* d_ws, size_t ws_size,
                              hipStream_t stream) {
    const float* x         = (const float*)d_in[0];
    const float* qkv_w     = (const float*)d_in[1];
    const float* qkv_b     = (const float*)d_in[2];
    const float* out_w     = (const float*)d_in[3];
    const float* pos_table = (const float*)d_in[4];
    float* y    = (float*)d_out;
    __bf16* mid = (__bf16*)d_ws;   // 2*9216*256 bf16 = 9.4 MB, pixel-major

    patch_attn<<<dim3(2304), dim3(256), 0, stream>>>(
        x, qkv_w, qkv_b, pos_table, mid);
    proj<<<dim3(72, 4, 2), dim3(256), 0, stream>>>(
        out_w, mid, y);
}

// Round 5
// 60.673 us; speedup vs baseline: 2.1745x; 1.1107x over previous
//
#include <hip/hip_runtime.h>

typedef float f4 __attribute__((ext_vector_type(4)));
typedef float f32x4 __attribute__((ext_vector_type(4)));
typedef __bf16 bf16x8 __attribute__((ext_vector_type(8)));
typedef __bf16 bf16x4 __attribute__((ext_vector_type(4)));

#define NPATCH 576
#define NPSIDE 24

// One wave per (b, head, patch). 4 waves per block, independent work.
__global__ __launch_bounds__(256) void patch_attn(
    const float* __restrict__ x,
    const float* __restrict__ qkv_w,
    const float* __restrict__ qkv_b,
    const float* __restrict__ pos_table,
    __bf16* __restrict__ mid)
{
    __shared__ __bf16 Kb[4][64][40];
    __shared__ __bf16 VT[4][32][72];
    __shared__ __bf16 Qb[4][16][40];
    __shared__ __bf16 Ps[4][16][72];

    const int t  = threadIdx.x;
    const int wv = t >> 6;
    const int l  = t & 63;

    int bid = blockIdx.x;
    bid = (bid & 7) * 288 + (bid >> 3);      // XCD swizzle, 2304 = 8*288
    const int gp    = bid * 4 + wv;
    const int patch = gp % NPATCH;
    const int bh    = gp / NPATCH;
    const int head  = bh & 7;
    const int b     = bh >> 3;
    const int ni = patch / NPSIDE, nj = patch % NPSIDE;
    const int c0 = head * 32;

    const int pi = l >> 3, pj = l & 7;
    const int row = min(4 * ni + pi, 95);    // edge padding
    const int col = min(4 * nj + pj, 95);
    const bool isq = (pi < 4) && (pj < 4);
    const int qr = (pi << 2) | pj;
    const float qscale = 0.17677669529663687f;

    const float* xptr = x + (((size_t)b * 256 + c0) * 96 + row) * 96 + col;

    #pragma unroll
    for (int d8 = 0; d8 < 4; ++d8) {
        bf16x8 kv, qv;
        #pragma unroll
        for (int j = 0; j < 8; ++j) {
            const int d = d8 * 8 + j;
            const int c = c0 + d;
            const float xv = xptr[(size_t)d * 9216];
            kv[j] = (__bf16)(xv * qkv_w[256 + c] + qkv_b[256 + c]);
            VT[wv][d][l] = (__bf16)(xv * qkv_w[512 + c] + qkv_b[512 + c]);
            qv[j] = (__bf16)((xv * qkv_w[c] + qkv_b[c]) * qscale);
        }
        *(bf16x8*)&Kb[wv][l][d8 * 8] = kv;
        if (isq) *(bf16x8*)&Qb[wv][qr][d8 * 8] = qv;
    }
    __syncthreads();

    // ---- QK^T: S(16x64) via 4 x mfma_16x16x32 ----
    const int l16 = l & 15, lg = l >> 4;
    const f32x4 zf = {0.f, 0.f, 0.f, 0.f};
    bf16x8 qf = *(const bf16x8*)&Qb[wv][l16][lg * 8];
    f32x4 sacc[4];
    #pragma unroll
    for (int t4 = 0; t4 < 4; ++t4) {
        bf16x8 kf = *(const bf16x8*)&Kb[wv][l16 + 16 * t4][lg * 8];
        sacc[t4] = __builtin_amdgcn_mfma_f32_16x16x32_bf16(qf, kf, zf, 0, 0, 0);
    }

    // ---- bias + row softmax ----
    float sv[4][4];
    float rinv[4];
    #pragma unroll
    for (int r = 0; r < 4; ++r) {
        const int qrow = lg * 4 + r;
        const int qi = qrow >> 2, qj = qrow & 3;
        float m = -1e30f;
        #pragma unroll
        for (int t4 = 0; t4 < 4; ++t4) {
            const int kcol = l16 + 16 * t4;
            const int ki = kcol >> 3, kj = kcol & 7;
            const float s = sacc[t4][r]
                + pos_table[((qi - ki + 7) * 15 + (qj - kj + 7)) * 8 + head];
            sv[t4][r] = s;
            m = fmaxf(m, s);
        }
        #pragma unroll
        for (int off = 8; off >= 1; off >>= 1)
            m = fmaxf(m, __shfl_xor(m, off, 16));
        float sum = 0.f;
        #pragma unroll
        for (int t4 = 0; t4 < 4; ++t4) {
            const float p = __expf(sv[t4][r] - m);
            sv[t4][r] = p;
            sum += p;
        }
        #pragma unroll
        for (int off = 8; off >= 1; off >>= 1)
            sum += __shfl_xor(sum, off, 16);
        rinv[r] = 1.0f / sum;
        #pragma unroll
        for (int t4 = 0; t4 < 4; ++t4)
            Ps[wv][qrow][l16 + 16 * t4] = (__bf16)sv[t4][r];
    }
    __syncthreads();

    // ---- PV: O(16x32) = P(16x64) * V(64x32) ----
    f32x4 oa = zf, ob = zf;
    #pragma unroll
    for (int kt = 0; kt < 2; ++kt) {
        bf16x8 pf = *(const bf16x8*)&Ps[wv][l16][lg * 8 + 32 * kt];
        bf16x8 v0 = *(const bf16x8*)&VT[wv][l16][lg * 8 + 32 * kt];
        bf16x8 v1 = *(const bf16x8*)&VT[wv][l16 + 16][lg * 8 + 32 * kt];
        oa = __builtin_amdgcn_mfma_f32_16x16x32_bf16(pf, v0, oa, 0, 0, 0);
        ob = __builtin_amdgcn_mfma_f32_16x16x32_bf16(pf, v1, ob, 0, 0, 0);
    }

    // mid layout: [b][patch*16 + qrow][c] bf16, c contiguous
    __bf16* mb = mid + ((size_t)b * 9216 + patch * 16) * 256 + c0;
    #pragma unroll
    for (int r = 0; r < 4; ++r) {
        const int qrow = lg * 4 + r;
        mb[(size_t)qrow * 256 + l16]      = (__bf16)(oa[r] * rinv[r]);
        mb[(size_t)qrow * 256 + 16 + l16] = (__bf16)(ob[r] * rinv[r]);
    }
}

// Convert out_w fp32 -> bf16 once (same RNE cast as before).
__global__ __launch_bounds__(256) void wcvt(
    const float* __restrict__ wmat, __bf16* __restrict__ wbf)
{
    const int i = (blockIdx.x * 256 + threadIdx.x) * 4;   // 65536 / 4 = 16384 threads
    const f4 v = *(const f4*)&wmat[i];
    bf16x4 o;
    #pragma unroll
    for (int j = 0; j < 4; ++j) o[j] = (__bf16)v[j];
    *(bf16x4*)&wbf[i] = o;
}

// y[b,o,pix] = sum_c w[o,c]*mid[b,pix,c]. Block: 64 o x 128 pix.
// Wave wv owns pix-sub [32*wv, 32*wv+32) x all 64 o -> mid tile read once
// per block; w slice (32 KB bf16) shared by 4 waves via L1/L2.
__global__ __launch_bounds__(256) void proj(
    const __bf16* __restrict__ wbf,   // [256][256] bf16
    const __bf16* __restrict__ mid,   // [B][9216][256] bf16
    float* __restrict__ y)
{
    const int t  = threadIdx.x;
    const int wv = t >> 6;
    const int l  = t & 63;
    const int l16 = l & 15, lg = l >> 4;

    int bx = blockIdx.x;
    bx = (bx & 7) * 9 + (bx >> 3);           // XCD swizzle, 72 = 8*9
    const int p0 = bx * 128 + wv * 32;       // wave's 32-pix strip
    const int o0 = blockIdx.y * 64;
    const int b  = blockIdx.z;

    const __bf16* midb = mid + (size_t)b * 9216 * 256;

    f32x4 acc[2][4];
    #pragma unroll
    for (int nt = 0; nt < 2; ++nt)
        #pragma unroll
        for (int ot = 0; ot < 4; ++ot) acc[nt][ot] = (f32x4){0.f, 0.f, 0.f, 0.f};

    #pragma unroll
    for (int kt = 0; kt < 8; ++kt) {
        const int cb = kt * 32 + lg * 8;
        bf16x8 af[4], bfr[2];
        #pragma unroll
        for (int ot = 0; ot < 4; ++ot)
            af[ot] = *(const bf16x8*)&wbf[(size_t)(o0 + ot * 16 + l16) * 256 + cb];
        #pragma unroll
        for (int nt = 0; nt < 2; ++nt)
            bfr[nt] = *(const bf16x8*)&midb[(size_t)(p0 + nt * 16 + l16) * 256 + cb];
        #pragma unroll
        for (int nt = 0; nt < 2; ++nt)
            #pragma unroll
            for (int ot = 0; ot < 4; ++ot)
                acc[nt][ot] = __builtin_amdgcn_mfma_f32_16x16x32_bf16(
                    af[ot], bfr[nt], acc[nt][ot], 0, 0, 0);
    }

    // D layout: col = l16 -> pix, row = lg*4+r -> o
    #pragma unroll
    for (int nt = 0; nt < 2; ++nt) {
        const int ps = p0 + nt * 16 + l16;
        const int patch = ps >> 4, qrr = ps & 15;
        const int hh = (patch / NPSIDE) * 4 + (qrr >> 2);
        const int ww = (patch % NPSIDE) * 4 + (qrr & 3);
        #pragma unroll
        for (int ot = 0; ot < 4; ++ot) {
            #pragma unroll
            for (int r = 0; r < 4; ++r) {
                const int o = o0 + ot * 16 + lg * 4 + r;
                y[((size_t)b * 256 + o) * 9216 + hh * 96 + ww] = acc[nt][ot][r];
            }
        }
    }
}

extern "C" void kernel_launch(void* const* d_in, const int* in_sizes, int n_in,
                              void* d_out, int out_size, void* d_ws, size_t ws_size,
                              hipStream_t stream) {
    const float* x         = (const float*)d_in[0];
    const float* qkv_w     = (const float*)d_in[1];
    const float* qkv_b     = (const float*)d_in[2];
    const float* out_w     = (const float*)d_in[3];
    const float* pos_table = (const float*)d_in[4];
    float* y    = (float*)d_out;
    __bf16* mid = (__bf16*)d_ws;                              // 9.4 MB
    __bf16* wbf = (__bf16*)((char*)d_ws + (12u << 20));       // 128 KB @ 12MB

    patch_attn<<<dim3(2304), dim3(256), 0, stream>>>(
        x, qkv_w, qkv_b, pos_table, mid);
    wcvt<<<dim3(64), dim3(256), 0, stream>>>(out_w, wbf);
    proj<<<dim3(72, 4, 2), dim3(256), 0, stream>>>(
        wbf, mid, y);
}

// Round 6
// 48.078 us; speedup vs baseline: 2.7441x; 1.2620x over previous
//
#include <hip/hip_runtime.h>

typedef float f4 __attribute__((ext_vector_type(4)));
typedef float f32x4 __attribute__((ext_vector_type(4)));
typedef __bf16 bf16x8 __attribute__((ext_vector_type(8)));
typedef __bf16 bf16x4 __attribute__((ext_vector_type(4)));

#define NPATCH 576
#define NPSIDE 24

// mid_t fragment-linear layout (per b): [ptile 0..575][kt 0..7][n 0..15][kc 0..31]
// where pixel p = hh*96+ww = ptile*16+n, channel c = kt*32+kc.
// wbf same: [otile 0..15][kt 0..7][m 0..15][kc 0..31], o = otile*16+m.

// One wave per (b, head, patch). 4 waves per block. Blocks 0..63 also
// convert out_w fp32 -> bf16 fragment-linear (side job, replaces wcvt kernel).
__global__ __launch_bounds__(256) void patch_attn(
    const float* __restrict__ x,
    const float* __restrict__ qkv_w,
    const float* __restrict__ qkv_b,
    const float* __restrict__ pos_table,
    const float* __restrict__ wmat,
    __bf16* __restrict__ mid,
    __bf16* __restrict__ wbf)
{
    __shared__ __bf16 Kb[4][64][40];
    __shared__ __bf16 VT[4][32][72];
    __shared__ __bf16 Qb[4][16][40];
    __shared__ __bf16 Ps[4][16][72];

    const int t  = threadIdx.x;
    const int wv = t >> 6;
    const int l  = t & 63;

    // side job: w -> bf16 fragment-linear
    if (blockIdx.x < 64) {
        const int i = (blockIdx.x * 256 + t) * 4;   // o*256+c, c%4==0
        const int o = i >> 8, c = i & 255;
        const f4 v = *(const f4*)&wmat[i];
        bf16x4 ov;
        #pragma unroll
        for (int j = 0; j < 4; ++j) ov[j] = (__bf16)v[j];
        *(bf16x4*)&wbf[((o >> 4) * 8 + (c >> 5)) * 512 + (o & 15) * 32 + (c & 31)] = ov;
    }

    int bid = blockIdx.x;
    bid = (bid & 7) * 288 + (bid >> 3);      // XCD swizzle, 2304 = 8*288
    const int gp    = bid * 4 + wv;
    const int patch = gp % NPATCH;
    const int bh    = gp / NPATCH;
    const int head  = bh & 7;
    const int b     = bh >> 3;
    const int ni = patch / NPSIDE, nj = patch % NPSIDE;
    const int c0 = head * 32;

    const int pi = l >> 3, pj = l & 7;
    const int row = min(4 * ni + pi, 95);    // edge padding
    const int col = min(4 * nj + pj, 95);
    const bool isq = (pi < 4) && (pj < 4);
    const int qr = (pi << 2) | pj;
    const float qscale = 0.17677669529663687f;

    const float* xptr = x + (((size_t)b * 256 + c0) * 96 + row) * 96 + col;

    #pragma unroll
    for (int d8 = 0; d8 < 4; ++d8) {
        bf16x8 kv, qv;
        #pragma unroll
        for (int j = 0; j < 8; ++j) {
            const int d = d8 * 8 + j;
            const int c = c0 + d;
            const float xv = xptr[(size_t)d * 9216];
            kv[j] = (__bf16)(xv * qkv_w[256 + c] + qkv_b[256 + c]);
            VT[wv][d][l] = (__bf16)(xv * qkv_w[512 + c] + qkv_b[512 + c]);
            qv[j] = (__bf16)((xv * qkv_w[c] + qkv_b[c]) * qscale);
        }
        *(bf16x8*)&Kb[wv][l][d8 * 8] = kv;
        if (isq) *(bf16x8*)&Qb[wv][qr][d8 * 8] = qv;
    }
    __syncthreads();

    // ---- QK^T: S(16x64) via 4 x mfma_16x16x32 ----
    const int l16 = l & 15, lg = l >> 4;
    const f32x4 zf = {0.f, 0.f, 0.f, 0.f};
    bf16x8 qf = *(const bf16x8*)&Qb[wv][l16][lg * 8];
    f32x4 sacc[4];
    #pragma unroll
    for (int t4 = 0; t4 < 4; ++t4) {
        bf16x8 kf = *(const bf16x8*)&Kb[wv][l16 + 16 * t4][lg * 8];
        sacc[t4] = __builtin_amdgcn_mfma_f32_16x16x32_bf16(qf, kf, zf, 0, 0, 0);
    }

    // ---- bias + row softmax ----
    float sv[4][4];
    float rinv[4];
    #pragma unroll
    for (int r = 0; r < 4; ++r) {
        const int qrow = lg * 4 + r;
        const int qi = qrow >> 2, qj = qrow & 3;
        float m = -1e30f;
        #pragma unroll
        for (int t4 = 0; t4 < 4; ++t4) {
            const int kcol = l16 + 16 * t4;
            const int ki = kcol >> 3, kj = kcol & 7;
            const float s = sacc[t4][r]
                + pos_table[((qi - ki + 7) * 15 + (qj - kj + 7)) * 8 + head];
            sv[t4][r] = s;
            m = fmaxf(m, s);
        }
        #pragma unroll
        for (int off = 8; off >= 1; off >>= 1)
            m = fmaxf(m, __shfl_xor(m, off, 16));
        float sum = 0.f;
        #pragma unroll
        for (int t4 = 0; t4 < 4; ++t4) {
            const float p = __expf(sv[t4][r] - m);
            sv[t4][r] = p;
            sum += p;
        }
        #pragma unroll
        for (int off = 8; off >= 1; off >>= 1)
            sum += __shfl_xor(sum, off, 16);
        rinv[r] = 1.0f / sum;
        #pragma unroll
        for (int t4 = 0; t4 < 4; ++t4)
            Ps[wv][qrow][l16 + 16 * t4] = (__bf16)sv[t4][r];
    }
    __syncthreads();

    // ---- PV: O(16x32) = P(16x64) * V(64x32) ----
    f32x4 oa = zf, ob = zf;
    #pragma unroll
    for (int kt = 0; kt < 2; ++kt) {
        bf16x8 pf = *(const bf16x8*)&Ps[wv][l16][lg * 8 + 32 * kt];
        bf16x8 v0 = *(const bf16x8*)&VT[wv][l16][lg * 8 + 32 * kt];
        bf16x8 v1 = *(const bf16x8*)&VT[wv][l16 + 16][lg * 8 + 32 * kt];
        oa = __builtin_amdgcn_mfma_f32_16x16x32_bf16(pf, v0, oa, 0, 0, 0);
        ob = __builtin_amdgcn_mfma_f32_16x16x32_bf16(pf, v1, ob, 0, 0, 0);
    }

    // ---- epilogue: store O to fragment-linear mid_t ----
    // qrow = lg*4+r -> qi = lg, qj = r. pixel p = ni*384 + lg*96 + nj*4 + r.
    // channel c = head*32 + kc, kc = l16 (oa) / 16+l16 (ob).
    const int pbase = ni * 384 + lg * 96 + nj * 4;
    __bf16* mbb = mid + (size_t)b * 9216 * 256;
    #pragma unroll
    for (int r = 0; r < 4; ++r) {
        const int p = pbase + r;
        __bf16* dst = mbb + ((p >> 4) * 8 + head) * 512 + (p & 15) * 32;
        dst[l16]      = (__bf16)(oa[r] * rinv[r]);
        dst[16 + l16] = (__bf16)(ob[r] * rinv[r]);
    }
}

// y[b,o,p] = sum_c w[o,c]*mid[b,p,c]; all operands fragment-linear ->
// every global load is 16 consecutive 64B lines. No LDS, no barriers.
// Block: 64 o x 128 pix; wave wv owns 2 ptiles (32 pix) x all 64 o.
__global__ __launch_bounds__(256) void proj(
    const __bf16* __restrict__ wbf,   // fragment-linear [16][8][512]
    const __bf16* __restrict__ mid,   // fragment-linear per b [576][8][512]
    float* __restrict__ y)
{
    const int t  = threadIdx.x;
    const int wv = t >> 6;
    const int l  = t & 63;
    const int l16 = l & 15, lg = l >> 4;
    const int fragoff = l16 * 32 + lg * 8;

    int bx = blockIdx.x;
    bx = (bx & 7) * 9 + (bx >> 3);           // XCD swizzle, 72 = 8*9
    const int pt0 = bx * 8 + wv * 2;         // wave's 2 ptiles
    const int ot0 = blockIdx.y * 4;          // 4 otiles (64 o)
    const int b   = blockIdx.z;

    const __bf16* midb = mid + (size_t)b * 9216 * 256;

    f32x4 acc[2][4];
    #pragma unroll
    for (int nt = 0; nt < 2; ++nt)
        #pragma unroll
        for (int ot = 0; ot < 4; ++ot) acc[nt][ot] = (f32x4){0.f, 0.f, 0.f, 0.f};

    #pragma unroll
    for (int kt = 0; kt < 8; ++kt) {
        bf16x8 af[4], bfr[2];
        #pragma unroll
        for (int ot = 0; ot < 4; ++ot)
            af[ot] = *(const bf16x8*)&wbf[((ot0 + ot) * 8 + kt) * 512 + fragoff];
        #pragma unroll
        for (int nt = 0; nt < 2; ++nt)
            bfr[nt] = *(const bf16x8*)&midb[(size_t)((pt0 + nt) * 8 + kt) * 512 + fragoff];
        #pragma unroll
        for (int nt = 0; nt < 2; ++nt)
            #pragma unroll
            for (int ot = 0; ot < 4; ++ot)
                acc[nt][ot] = __builtin_amdgcn_mfma_f32_16x16x32_bf16(
                    af[ot], bfr[nt], acc[nt][ot], 0, 0, 0);
    }

    // D: row = lg*4+r -> o-in-tile, col = l16 -> pixel-in-tile (contiguous)
    #pragma unroll
    for (int nt = 0; nt < 2; ++nt) {
        const int p = (pt0 + nt) * 16 + l16;
        #pragma unroll
        for (int ot = 0; ot < 4; ++ot) {
            const int o = (ot0 + ot) * 16 + lg * 4;
            float* yb = y + ((size_t)b * 256 + o) * 9216 + p;
            #pragma unroll
            for (int r = 0; r < 4; ++r)
                yb[(size_t)r * 9216] = acc[nt][ot][r];
        }
    }
}

extern "C" void kernel_launch(void* const* d_in, const int* in_sizes, int n_in,
                              void* d_out, int out_size, void* d_ws, size_t ws_size,
                              hipStream_t stream) {
    const float* x         = (const float*)d_in[0];
    const float* qkv_w     = (const float*)d_in[1];
    const float* qkv_b     = (const float*)d_in[2];
    const float* out_w     = (const float*)d_in[3];
    const float* pos_table = (const float*)d_in[4];
    float* y    = (float*)d_out;
    __bf16* mid = (__bf16*)d_ws;                              // 9.4 MB
    __bf16* wbf = (__bf16*)((char*)d_ws + (12u << 20));       // 128 KB @ 12MB

    patch_attn<<<dim3(2304), dim3(256), 0, stream>>>(
        x, qkv_w, qkv_b, pos_table, out_w, mid, wbf);
    proj<<<dim3(72, 4, 2), dim3(256), 0, stream>>>(
        wbf, mid, y);
}

// Round 7
// 43.580 us; speedup vs baseline: 3.0273x; 1.1032x over previous
//
#include <hip/hip_runtime.h>

typedef float f4 __attribute__((ext_vector_type(4)));
typedef float f32x4 __attribute__((ext_vector_type(4)));
typedef __bf16 bf16x8 __attribute__((ext_vector_type(8)));
typedef __bf16 bf16x4 __attribute__((ext_vector_type(4)));

#define NPSIDE 24

// Block = (b, head, 2x4 patch group), 512 threads = 8 waves.
// Wave wv -> patch (ni0 + (wv>>2), nj0 + (wv&3)).
// Shared region xs: rows 4*ni0..+11 (12), cols 4*nj0..+19 (20), 32 ch, fp32,
// clamping baked in at stage time. Plane stride 253 (=12*21+1) spreads banks.
// Q/K/V fragments are built by transform-at-read from xs (coeffs in VGPRs).
#define XS(ch_, r_, c_) xs[(ch_) * 253 + (r_) * 21 + (c_)]

__global__ __launch_bounds__(512, 4) void patch_attn(
    const float* __restrict__ x,
    const float* __restrict__ qkv_w,
    const float* __restrict__ qkv_b,
    const float* __restrict__ pos_table,
    const float* __restrict__ wmat,
    __bf16* __restrict__ mid,
    __bf16* __restrict__ wbf)
{
    __shared__ float xs[32 * 253];           // 32.4 KB
    __shared__ __bf16 Ps[8][16][72];         // 18.4 KB

    const int t = threadIdx.x;

    // side job: out_w fp32 -> bf16 fragment-linear (blocks 0..31, raw id)
    if (blockIdx.x < 32) {
        const int i = (blockIdx.x * 512 + t) * 4;   // o*256+c
        const int o = i >> 8, c = i & 255;
        const f4 v = *(const f4*)&wmat[i];
        bf16x4 ov;
        #pragma unroll
        for (int j = 0; j < 4; ++j) ov[j] = (__bf16)v[j];
        *(bf16x4*)&wbf[((o >> 4) * 8 + (c >> 5)) * 512 + (o & 15) * 32 + (c & 31)] = ov;
    }

    int raw = blockIdx.x;
    const int sw = (raw & 7) * 144 + (raw >> 3);    // XCD swizzle, 1152 = 8*144
    const int pgrp = sw % 72;
    const int bh   = sw / 72;
    const int head = bh & 7;
    const int b    = bh >> 3;
    const int ni0  = (pgrp / 6) * 2;
    const int nj0  = (pgrp % 6) * 4;
    const int c0   = head * 32;

    // ---- stage shared region (384 threads, 5 f4 each, coalesced runs) ----
    if (t < 384) {
        const int ch  = t / 12;
        const int row = t % 12;
        const int rg  = min(4 * ni0 + row, 95);
        const float* xrow = x + (((size_t)b * 256 + c0 + ch) * 96 + rg) * 96;
        float* xdst = &XS(ch, row, 0);
        const int cb = 4 * nj0;
        #pragma unroll
        for (int cg = 0; cg < 5; ++cg) {
            const int cg4 = cb + cg * 4;
            f4 v;
            if (cg4 <= 92) {
                v = *(const f4*)&xrow[cg4];
            } else {                         // cols 96..99 -> clamp to col 95
                f4 u = *(const f4*)&xrow[92];
                v = (f4){u.w, u.w, u.w, u.w};
            }
            xdst[cg * 4 + 0] = v.x;
            xdst[cg * 4 + 1] = v.y;
            xdst[cg * 4 + 2] = v.z;
            xdst[cg * 4 + 3] = v.w;
        }
    }

    // per-lane affine coefficients (registers)
    const int wv = t >> 6, l = t & 63;
    const int l16 = l & 15, lg = l >> 4;
    const float qscale = 0.17677669529663687f;

    float kw8[8], kb8[8], qw8[8], qb8[8];
    #pragma unroll
    for (int j = 0; j < 8; ++j) {
        const int c = c0 + 8 * lg + j;
        kw8[j] = qkv_w[256 + c];
        kb8[j] = qkv_b[256 + c];
        qw8[j] = qkv_w[c] * qscale;
        qb8[j] = qkv_b[c] * qscale;
    }
    float vw2[2], vb2[2];
    #pragma unroll
    for (int nt = 0; nt < 2; ++nt) {
        const int c = c0 + nt * 16 + l16;
        vw2[nt] = qkv_w[512 + c];
        vb2[nt] = qkv_b[512 + c];
    }

    __syncthreads();

    const int wni = wv >> 2, wnj = wv & 3;
    const int ni = ni0 + wni, nj = nj0 + wnj;
    const int rb = 4 * wni, cbl = 4 * wnj;   // patch origin within region

    // ---- Q fragment (row = l16, ch = 8lg+j) ----
    bf16x8 qf;
    {
        const int qrow = rb + (l16 >> 2), qcol = cbl + (l16 & 3);
        #pragma unroll
        for (int j = 0; j < 8; ++j)
            qf[j] = (__bf16)(XS(8 * lg + j, qrow, qcol) * qw8[j] + qb8[j]);
    }

    // ---- QK^T: build K fragment per t4 and mfma ----
    const f32x4 zf = {0.f, 0.f, 0.f, 0.f};
    f32x4 sacc[4];
    #pragma unroll
    for (int t4 = 0; t4 < 4; ++t4) {
        const int px = l16 + 16 * t4;
        const int kr = rb + (px >> 3), kc = cbl + (px & 7);
        bf16x8 kf;
        #pragma unroll
        for (int j = 0; j < 8; ++j)
            kf[j] = (__bf16)(XS(8 * lg + j, kr, kc) * kw8[j] + kb8[j]);
        sacc[t4] = __builtin_amdgcn_mfma_f32_16x16x32_bf16(qf, kf, zf, 0, 0, 0);
    }

    // ---- bias + row softmax ----
    float sv[4][4], rinv[4];
    #pragma unroll
    for (int r = 0; r < 4; ++r) {
        const int qrow = lg * 4 + r;
        const int qi = qrow >> 2, qj = qrow & 3;
        float m = -1e30f;
        #pragma unroll
        for (int t4 = 0; t4 < 4; ++t4) {
            const int kcol = l16 + 16 * t4;
            const int ki = kcol >> 3, kj = kcol & 7;
            const float s = sacc[t4][r]
                + pos_table[((qi - ki + 7) * 15 + (qj - kj + 7)) * 8 + head];
            sv[t4][r] = s;
            m = fmaxf(m, s);
        }
        #pragma unroll
        for (int off = 8; off >= 1; off >>= 1)
            m = fmaxf(m, __shfl_xor(m, off, 16));
        float sum = 0.f;
        #pragma unroll
        for (int t4 = 0; t4 < 4; ++t4) {
            const float p = __expf(sv[t4][r] - m);
            sv[t4][r] = p;
            sum += p;
        }
        #pragma unroll
        for (int off = 8; off >= 1; off >>= 1)
            sum += __shfl_xor(sum, off, 16);
        rinv[r] = 1.0f / sum;
        #pragma unroll
        for (int t4 = 0; t4 < 4; ++t4)
            Ps[wv][qrow][l16 + 16 * t4] = (__bf16)sv[t4][r];
    }
    // Ps is wave-private: compiler's lgkmcnt ordering suffices, no barrier.

    // ---- PV: build V fragments from xs and mfma ----
    f32x4 oa = zf, ob = zf;
    #pragma unroll
    for (int kt = 0; kt < 2; ++kt) {
        bf16x8 pf = *(const bf16x8*)&Ps[wv][l16][lg * 8 + 32 * kt];
        bf16x8 v0, v1;
        #pragma unroll
        for (int j = 0; j < 8; ++j) {
            const int px = kt * 32 + 8 * lg + j;
            const int vr = rb + (px >> 3), vc = cbl + (px & 7);
            v0[j] = (__bf16)(XS(l16,      vr, vc) * vw2[0] + vb2[0]);
            v1[j] = (__bf16)(XS(16 + l16, vr, vc) * vw2[1] + vb2[1]);
        }
        oa = __builtin_amdgcn_mfma_f32_16x16x32_bf16(pf, v0, oa, 0, 0, 0);
        ob = __builtin_amdgcn_mfma_f32_16x16x32_bf16(pf, v1, ob, 0, 0, 0);
    }

    // ---- epilogue: store O to fragment-linear mid ----
    const int pbase = ni * 384 + lg * 96 + nj * 4;
    __bf16* mbb = mid + (size_t)b * 9216 * 256;
    #pragma unroll
    for (int r = 0; r < 4; ++r) {
        const int p = pbase + r;
        __bf16* dst = mbb + ((p >> 4) * 8 + head) * 512 + (p & 15) * 32;
        dst[l16]      = (__bf16)(oa[r] * rinv[r]);
        dst[16 + l16] = (__bf16)(ob[r] * rinv[r]);
    }
}

// y[b,o,p] = sum_c w[o,c]*mid[b,p,c]; fragment-linear operands, no LDS.
// Wave = 1 ptile x 2 otiles (4608 waves). Block's 4 waves share w frags.
// XCD swizzle: each XCD sweeps 72 ptiles x all 8 otile-pairs -> L2-local.
__global__ __launch_bounds__(256) void proj(
    const __bf16* __restrict__ wbf,   // fragment-linear [16][8][512]
    const __bf16* __restrict__ mid,   // fragment-linear per b [576][8][512]
    float* __restrict__ y)
{
    const int t  = threadIdx.x;
    const int wv = t >> 6;
    const int l  = t & 63;
    const int l16 = l & 15, lg = l >> 4;
    const int fragoff = l16 * 32 + lg * 8;

    int raw = blockIdx.x;                     // 0..1151
    const int sw  = (raw & 7) * 144 + (raw >> 3);
    const int ptg = sw >> 3;                  // 0..143
    const int og2 = sw & 7;                   // 0..7
    const int pt  = ptg * 4 + wv;             // 0..575
    const int ot0 = og2 * 2;
    const int b   = blockIdx.z;

    const __bf16* midb = mid + (size_t)b * 9216 * 256;

    f32x4 acc0 = {0.f, 0.f, 0.f, 0.f}, acc1 = {0.f, 0.f, 0.f, 0.f};

    #pragma unroll
    for (int kt = 0; kt < 8; ++kt) {
        const bf16x8 bfr =
            *(const bf16x8*)&midb[(size_t)(pt * 8 + kt) * 512 + fragoff];
        const bf16x8 af0 = *(const bf16x8*)&wbf[((ot0 + 0) * 8 + kt) * 512 + fragoff];
        const bf16x8 af1 = *(const bf16x8*)&wbf[((ot0 + 1) * 8 + kt) * 512 + fragoff];
        acc0 = __builtin_amdgcn_mfma_f32_16x16x32_bf16(af0, bfr, acc0, 0, 0, 0);
        acc1 = __builtin_amdgcn_mfma_f32_16x16x32_bf16(af1, bfr, acc1, 0, 0, 0);
    }

    const int p = pt * 16 + l16;
    #pragma unroll
    for (int ot = 0; ot < 2; ++ot) {
        const f32x4 a = ot ? acc1 : acc0;
        const int o = (ot0 + ot) * 16 + lg * 4;
        float* yb = y + ((size_t)b * 256 + o) * 9216 + p;
        #pragma unroll
        for (int r = 0; r < 4; ++r)
            yb[(size_t)r * 9216] = a[r];
    }
}

extern "C" void kernel_launch(void* const* d_in, const int* in_sizes, int n_in,
                              void* d_out, int out_size, void* d_ws, size_t ws_size,
                              hipStream_t stream) {
    const float* x         = (const float*)d_in[0];
    const float* qkv_w     = (const float*)d_in[1];
    const float* qkv_b     = (const float*)d_in[2];
    const float* out_w     = (const float*)d_in[3];
    const float* pos_table = (const float*)d_in[4];
    float* y    = (float*)d_out;
    __bf16* mid = (__bf16*)d_ws;                              // 9.4 MB
    __bf16* wbf = (__bf16*)((char*)d_ws + (12u << 20));       // 128 KB @ 12MB

    patch_attn<<<dim3(1152), dim3(512), 0, stream>>>(
        x, qkv_w, qkv_b, pos_table, out_w, mid, wbf);
    proj<<<dim3(1152, 1, 2), dim3(256), 0, stream>>>(
        wbf, mid, y);
}

// Round 8
// 37.028 us; speedup vs baseline: 3.5630x; 1.1770x over previous
//
#include <hip/hip_runtime.h>

typedef float f4 __attribute__((ext_vector_type(4)));
typedef float f32x4 __attribute__((ext_vector_type(4)));
typedef __bf16 bf16x8 __attribute__((ext_vector_type(8)));
typedef __bf16 bf16x4 __attribute__((ext_vector_type(4)));

#define NPSIDE 24

// Block = (b, head, 2x4 patch group), 512 threads = 8 waves.
// Wave wv -> patch (ni0 + (wv>>2), nj0 + (wv&3)).
// Shared region xs: rows 4*ni0..+11 (12), cols 4*nj0..+19 (20), 32 ch, fp32,
// clamping baked in at stage time. Plane stride 253 (=12*21+1) spreads banks.
// Q/K/V fragments are built by transform-at-read from xs (coeffs in VGPRs).
#define XS(ch_, r_, c_) xs[(ch_) * 253 + (r_) * 21 + (c_)]

__global__ __launch_bounds__(512, 2) void patch_attn(
    const float* __restrict__ x,
    const float* __restrict__ qkv_w,
    const float* __restrict__ qkv_b,
    const float* __restrict__ pos_table,
    const float* __restrict__ wmat,
    __bf16* __restrict__ mid,
    __bf16* __restrict__ wbf)
{
    __shared__ float xs[32 * 253];           // 32.4 KB
    __shared__ __bf16 Ps[8][16][72];         // 18.4 KB

    const int t = threadIdx.x;

    // side job: out_w fp32 -> bf16 fragment-linear (blocks 0..31, raw id)
    if (blockIdx.x < 32) {
        const int i = (blockIdx.x * 512 + t) * 4;   // o*256+c
        const int o = i >> 8, c = i & 255;
        const f4 v = *(const f4*)&wmat[i];
        bf16x4 ov;
        #pragma unroll
        for (int j = 0; j < 4; ++j) ov[j] = (__bf16)v[j];
        *(bf16x4*)&wbf[((o >> 4) * 8 + (c >> 5)) * 512 + (o & 15) * 32 + (c & 31)] = ov;
    }

    int raw = blockIdx.x;
    const int sw = (raw & 7) * 144 + (raw >> 3);    // XCD swizzle, 1152 = 8*144
    const int pgrp = sw % 72;
    const int bh   = sw / 72;
    const int head = bh & 7;
    const int b    = bh >> 3;
    const int ni0  = (pgrp / 6) * 2;
    const int nj0  = (pgrp % 6) * 4;
    const int c0   = head * 32;

    // ---- stage shared region (384 threads, 5 f4 each) ----
    if (t < 384) {
        const int ch  = t / 12;
        const int row = t % 12;
        const int rg  = min(4 * ni0 + row, 95);
        const float* xrow = x + (((size_t)b * 256 + c0 + ch) * 96 + rg) * 96;
        float* xdst = &XS(ch, row, 0);
        const int cb = 4 * nj0;
        #pragma unroll
        for (int cg = 0; cg < 5; ++cg) {
            const int cg4 = cb + cg * 4;
            f4 v;
            if (cg4 <= 92) {
                v = *(const f4*)&xrow[cg4];
            } else {                         // cols 96..99 -> clamp to col 95
                f4 u = *(const f4*)&xrow[92];
                v = (f4){u.w, u.w, u.w, u.w};
            }
            xdst[cg * 4 + 0] = v.x;
            xdst[cg * 4 + 1] = v.y;
            xdst[cg * 4 + 2] = v.z;
            xdst[cg * 4 + 3] = v.w;
        }
    }

    // per-lane affine coefficients (registers)
    const int wv = t >> 6, l = t & 63;
    const int l16 = l & 15, lg = l >> 4;
    const float qscale = 0.17677669529663687f;

    float kw8[8], kb8[8], qw8[8], qb8[8];
    #pragma unroll
    for (int j = 0; j < 8; ++j) {
        const int c = c0 + 8 * lg + j;
        kw8[j] = qkv_w[256 + c];
        kb8[j] = qkv_b[256 + c];
        qw8[j] = qkv_w[c] * qscale;
        qb8[j] = qkv_b[c] * qscale;
    }
    float vw2[2], vb2[2];
    #pragma unroll
    for (int nt = 0; nt < 2; ++nt) {
        const int c = c0 + nt * 16 + l16;
        vw2[nt] = qkv_w[512 + c];
        vb2[nt] = qkv_b[512 + c];
    }

    __syncthreads();

    const int wni = wv >> 2, wnj = wv & 3;
    const int ni = ni0 + wni, nj = nj0 + wnj;
    const int rb = 4 * wni, cbl = 4 * wnj;   // patch origin within region

    // ---- Q fragment (row = l16, ch = 8lg+j) ----
    bf16x8 qf;
    {
        const int qrow = rb + (l16 >> 2), qcol = cbl + (l16 & 3);
        #pragma unroll
        for (int j = 0; j < 8; ++j)
            qf[j] = (__bf16)(XS(8 * lg + j, qrow, qcol) * qw8[j] + qb8[j]);
    }

    // ---- QK^T: build K fragment per t4 and mfma ----
    const f32x4 zf = {0.f, 0.f, 0.f, 0.f};
    f32x4 sacc[4];
    #pragma unroll
    for (int t4 = 0; t4 < 4; ++t4) {
        const int px = l16 + 16 * t4;
        const int kr = rb + (px >> 3), kc = cbl + (px & 7);
        bf16x8 kf;
        #pragma unroll
        for (int j = 0; j < 8; ++j)
            kf[j] = (__bf16)(XS(8 * lg + j, kr, kc) * kw8[j] + kb8[j]);
        sacc[t4] = __builtin_amdgcn_mfma_f32_16x16x32_bf16(qf, kf, zf, 0, 0, 0);
    }

    // ---- bias + row softmax ----
    float sv[4][4], rinv[4];
    #pragma unroll
    for (int r = 0; r < 4; ++r) {
        const int qrow = lg * 4 + r;
        const int qi = qrow >> 2, qj = qrow & 3;
        float m = -1e30f;
        #pragma unroll
        for (int t4 = 0; t4 < 4; ++t4) {
            const int kcol = l16 + 16 * t4;
            const int ki = kcol >> 3, kj = kcol & 7;
            const float s = sacc[t4][r]
                + pos_table[((qi - ki + 7) * 15 + (qj - kj + 7)) * 8 + head];
            sv[t4][r] = s;
            m = fmaxf(m, s);
        }
        #pragma unroll
        for (int off = 8; off >= 1; off >>= 1)
            m = fmaxf(m, __shfl_xor(m, off, 16));
        float sum = 0.f;
        #pragma unroll
        for (int t4 = 0; t4 < 4; ++t4) {
            const float p = __expf(sv[t4][r] - m);
            sv[t4][r] = p;
            sum += p;
        }
        #pragma unroll
        for (int off = 8; off >= 1; off >>= 1)
            sum += __shfl_xor(sum, off, 16);
        rinv[r] = 1.0f / sum;
        #pragma unroll
        for (int t4 = 0; t4 < 4; ++t4)
            Ps[wv][qrow][l16 + 16 * t4] = (__bf16)sv[t4][r];
    }
    // Ps is wave-private: compiler's lgkmcnt ordering suffices, no barrier.

    // ---- PV: build V fragments from xs and mfma ----
    f32x4 oa = zf, ob = zf;
    #pragma unroll
    for (int kt = 0; kt < 2; ++kt) {
        bf16x8 pf = *(const bf16x8*)&Ps[wv][l16][lg * 8 + 32 * kt];
        bf16x8 v0, v1;
        #pragma unroll
        for (int j = 0; j < 8; ++j) {
            const int px = kt * 32 + 8 * lg + j;
            const int vr = rb + (px >> 3), vc = cbl + (px & 7);
            v0[j] = (__bf16)(XS(l16,      vr, vc) * vw2[0] + vb2[0]);
            v1[j] = (__bf16)(XS(16 + l16, vr, vc) * vw2[1] + vb2[1]);
        }
        oa = __builtin_amdgcn_mfma_f32_16x16x32_bf16(pf, v0, oa, 0, 0, 0);
        ob = __builtin_amdgcn_mfma_f32_16x16x32_bf16(pf, v1, ob, 0, 0, 0);
    }

    // ---- epilogue: store O to fragment-linear mid ----
    const int pbase = ni * 384 + lg * 96 + nj * 4;
    __bf16* mbb = mid + (size_t)b * 9216 * 256;
    #pragma unroll
    for (int r = 0; r < 4; ++r) {
        const int p = pbase + r;
        __bf16* dst = mbb + ((p >> 4) * 8 + head) * 512 + (p & 15) * 32;
        dst[l16]      = (__bf16)(oa[r] * rinv[r]);
        dst[16 + l16] = (__bf16)(ob[r] * rinv[r]);
    }
}

// y[b,o,p] = sum_c w[o,c]*mid[b,p,c]; fragment-linear operands.
// Block = 4 ptiles x 2 otiles; the 16 KB w-pair is staged in LDS once
// (was: every wave re-loading it from global = 2/3 of all loads).
// Wave wv -> ptile pt, global loads = 8 coalesced mid fragments only.
__global__ __launch_bounds__(256) void proj(
    const __bf16* __restrict__ wbf,   // fragment-linear [16][8][512]
    const __bf16* __restrict__ mid,   // fragment-linear per b [576][8][512]
    float* __restrict__ y)
{
    __shared__ __align__(16) __bf16 wlds[2][8][512];   // 16 KB

    const int t  = threadIdx.x;
    const int wv = t >> 6;
    const int l  = t & 63;
    const int l16 = l & 15, lg = l >> 4;
    const int fragoff = l16 * 32 + lg * 8;

    int raw = blockIdx.x;                     // 0..1151
    const int sw  = (raw & 7) * 144 + (raw >> 3);
    const int ptg = sw >> 3;                  // 0..143
    const int og2 = sw & 7;                   // 0..7
    const int pt  = ptg * 4 + wv;             // 0..575
    const int ot0 = og2 * 2;
    const int b   = blockIdx.z;

    // stage w pair (fully coalesced: 4 KB per instruction)
    {
        const bf16x8* wsrc = (const bf16x8*)&wbf[(size_t)ot0 * 8 * 512];
        bf16x8* wdst = (bf16x8*)&wlds[0][0][0];
        #pragma unroll
        for (int i = 0; i < 4; ++i)
            wdst[t + 256 * i] = wsrc[t + 256 * i];
    }
    __syncthreads();

    const __bf16* midb = mid + (size_t)b * 9216 * 256;

    f32x4 acc0 = {0.f, 0.f, 0.f, 0.f}, acc1 = {0.f, 0.f, 0.f, 0.f};

    #pragma unroll
    for (int kt = 0; kt < 8; ++kt) {
        const bf16x8 bfr =
            *(const bf16x8*)&midb[(size_t)(pt * 8 + kt) * 512 + fragoff];
        const bf16x8 af0 = *(const bf16x8*)&wlds[0][kt][fragoff];
        const bf16x8 af1 = *(const bf16x8*)&wlds[1][kt][fragoff];
        acc0 = __builtin_amdgcn_mfma_f32_16x16x32_bf16(af0, bfr, acc0, 0, 0, 0);
        acc1 = __builtin_amdgcn_mfma_f32_16x16x32_bf16(af1, bfr, acc1, 0, 0, 0);
    }

    const int p = pt * 16 + l16;
    #pragma unroll
    for (int ot = 0; ot < 2; ++ot) {
        const f32x4 a = ot ? acc1 : acc0;
        const int o = (ot0 + ot) * 16 + lg * 4;
        float* yb = y + ((size_t)b * 256 + o) * 9216 + p;
        #pragma unroll
        for (int r = 0; r < 4; ++r)
            yb[(size_t)r * 9216] = a[r];
    }
}

extern "C" void kernel_launch(void* const* d_in, const int* in_sizes, int n_in,
                              void* d_out, int out_size, void* d_ws, size_t ws_size,
                              hipStream_t stream) {
    const float* x         = (const float*)d_in[0];
    const float* qkv_w     = (const float*)d_in[1];
    const float* qkv_b     = (const float*)d_in[2];
    const float* out_w     = (const float*)d_in[3];
    const float* pos_table = (const float*)d_in[4];
    float* y    = (float*)d_out;
    __bf16* mid = (__bf16*)d_ws;                              // 9.4 MB
    __bf16* wbf = (__bf16*)((char*)d_ws + (12u << 20));       // 128 KB @ 12MB

    patch_attn<<<dim3(1152), dim3(512), 0, stream>>>(
        x, qkv_w, qkv_b, pos_table, out_w, mid, wbf);
    proj<<<dim3(1152, 1, 2), dim3(256), 0, stream>>>(
        wbf, mid, y);
}